// Round 20
// baseline (25.220 us; speedup 1.0000x reference)
//
#include <hip/hip_runtime.h>

#define TT 16384
#define BB 32

typedef __attribute__((ext_vector_type(8))) short bf16x8;
typedef __attribute__((ext_vector_type(4))) float f32x4;

#define S1 2.8853900817779268f   // 2*log2(e)

__device__ __forceinline__ unsigned short f2bf(float v) {   // RNE, weights only
    unsigned int u = __float_as_uint(v);
    u = (u + 0x7fffu + ((u >> 16) & 1u)) >> 16;
    return (unsigned short)u;
}
__device__ __forceinline__ unsigned int pk2(float lo, float hi) {   // RNE pack (weights)
    return (unsigned)f2bf(lo) | ((unsigned)f2bf(hi) << 16);
}
// HOT pack: truncating, 1 VALU (v_perm_b32)
__device__ __forceinline__ unsigned int pk2t(float lo, float hi) {
#if __has_builtin(__builtin_amdgcn_perm)
    return __builtin_amdgcn_perm(__float_as_uint(hi), __float_as_uint(lo), 0x07060302u);
#else
    return (__float_as_uint(hi) & 0xFFFF0000u) | (__float_as_uint(lo) >> 16);
#endif
}
__device__ __forceinline__ float rcore(float v) {   // r = 1/(exp2(v)+1); tanh = 1-2r
    return __builtin_amdgcn_rcpf(__builtin_amdgcn_exp2f(v) + 1.0f);
}

// ---------------- single fused kernel, 64 pos/wave, grid 2048, LDS ~20KB ----------------
// Occupancy push: grid 2048 (8 blocks/CU of work) + weight tables OVERLAID into
// the G ring region (tables dead after A-gather; extra __syncthreads orders
// wave-0 G-writes after all waves' table reads). Ring addressing = round-10
// verified: S 64-row ring (tail rows 64..66 staged at p==1 into slots 0..2),
// G 32-col ring.
__device__ __forceinline__ void stage_row(char* S, const float* __restrict__ x,
                                          int b, int tb, int i) {
    const int trow = tb - 3 + i;
    uint4 h0 = {0u, 0u, 0u, 0u}, h1 = {0u, 0u, 0u, 0u};
    if (trow >= 0 && trow < TT) {
        const float4* p = (const float4*)x + (size_t)(b * TT + trow) * 4;
        float4 f0 = p[0], f1 = p[1], f2 = p[2], f3 = p[3];
        h0.x = pk2t(f0.x, f0.y); h0.y = pk2t(f0.z, f0.w);
        h0.z = pk2t(f1.x, f1.y); h0.w = pk2t(f1.z, f1.w);
        h1.x = pk2t(f2.x, f2.y); h1.y = pk2t(f2.z, f2.w);
        h1.z = pk2t(f3.x, f3.y); h1.w = pk2t(f3.z, f3.w);
    }
    const int s = (i >> 2) & 1;
    char* base = S + (i & 63) * 32;
    *(uint4*)(base + s * 16) = h0;
    *(uint4*)(base + (s ^ 1) * 16) = h1;
}

#define MFMA16(a, bb, cc) __builtin_amdgcn_mfma_f32_16x16x32_bf16((a), (bb), (cc), 0, 0, 0)
#define GPLANE 512   // 32 cols * 16B

__global__ __launch_bounds__(256, 2) void rvt_one(
    const float* __restrict__ x,
    const float* __restrict__ conv_w, const float* __restrict__ conv_b,
    const float* __restrict__ fc_hid_w, const float* __restrict__ fc_hid_b,
    const float* __restrict__ fc_out_w, const float* __restrict__ fc_out_b,
    float* __restrict__ out)
{
    __shared__ __align__(16) char Sbuf[4 * 2048];
    __shared__ __align__(16) char Gbuf[4 * 3072];   // tables overlaid at Gbuf[0..4607]
    __shared__ float Small[23];

    float* CwPad  = (float*)Gbuf;           // 576 floats (2304 B) — prologue only
    float* FhwPad = (float*)(Gbuf + 2304);  // 576 floats — prologue only

    const int tid = threadIdx.x, wv = tid >> 6, l = tid & 63;
    const int n = l & 15, g = l >> 4;
    const int m = n;
    const int P0 = blockIdx.x << 8;               // 256 positions per block
    const int b  = P0 >> 14;
    const int tb = (P0 & (TT - 1)) + (wv << 6);   // 64 positions per wave

    char* S = Sbuf + wv * 2048;
    char* G = Gbuf + wv * 3072;

    // ---- prologue: stage rows 0..63 (rows tb-3 .. tb+60) ----
    stage_row(S, x, b, tb, l);

    // ---- build pre-scaled weight tables (in overlaid region) ----
    for (int i = tid; i < 576; i += 256) FhwPad[i] = S1 * fc_hid_w[i];
    for (int s = tid; s < 576; s += 256) {
        const int r = (s / 48) & 3, kcp = s % 48;
        if (!(r < 3 && kcp >= 14 && kcp <= 16)) CwPad[s] = 0.f;
    }
    if (tid < 27) {
        const int mt = tid / 9, r = (tid % 9) / 3, kc = tid % 3;
        CwPad[(mt * 4 + r) * 48 + 14 + kc] = S1 * conv_w[tid];
    } else if (tid < 30) Small[tid - 27] = S1 * conv_b[tid - 27];
    else if (tid < 36) Small[3 + tid - 30] = S1 * fc_hid_b[tid - 30];
    else if (tid < 48) Small[9 + tid - 36] = fc_out_w[tid - 36];
    else if (tid < 50) Small[21 + tid - 48] = fc_out_b[tid - 48];
    __syncthreads();

    // ---- per-lane A-fragment gather from LDS (RNE; one-time) ----
    union { uint4 u; bf16x8 f; } cv;
    bf16x8 A1[6], A2[3];
    #pragma unroll
    for (int mt = 0; mt < 3; ++mt)
        #pragma unroll
        for (int kt = 0; kt < 2; ++kt) {
            const int rr = kt * 2 + (g >> 1);
            const float* p = &CwPad[(mt * 4 + rr) * 48 + ((g & 1) * 8 - m + 15)];
            cv.u.x = pk2(p[0], p[1]);
            cv.u.y = pk2(p[2], p[3]);
            cv.u.z = pk2(p[4], p[5]);
            cv.u.w = pk2(p[6], p[7]);
            A1[mt * 2 + kt] = cv.f;
        }
    {
        const unsigned umask = (m < 6) ? 0xFFFFFFFFu : 0u;
        const int mc = (m < 6) ? m : 5;
        #pragma unroll
        for (int kt2 = 0; kt2 < 3; ++kt2) {
            const int q0 = kt2 * 32 + g * 8;
            const int wr = (q0 >= 48) ? 1 : 0;
            const int col0 = q0 - 48 * wr;
            const int oc = col0 >> 4, c0 = col0 & 15;
            const float4* fp = (const float4*)&FhwPad[mc * 96 + (oc * 2 + wr) * 16 + c0];
            float4 a = fp[0], bq = fp[1];
            cv.u.x = pk2(a.x, a.y) & umask;
            cv.u.y = pk2(a.z, a.w) & umask;
            cv.u.z = pk2(bq.x, bq.y) & umask;
            cv.u.w = pk2(bq.z, bq.w) & umask;
            A2[kt2] = cv.f;
        }
    }

    const float cbs0 = Small[0], cbs1 = Small[1], cbs2 = Small[2];
    const int r0 = g * 4;
    const float b1i0 = (r0 + 0 < 6) ? Small[3 + r0 + 0] : 0.f;
    const float b1i1 = (r0 + 1 < 6) ? Small[3 + r0 + 1] : 0.f;
    const float b1i2 = (r0 + 2 < 6) ? Small[3 + r0 + 2] : 0.f;
    const float b1i3 = (r0 + 3 < 6) ? Small[3 + r0 + 3] : 0.f;
    const float w200 = Small[9],  w201 = Small[10], w202 = Small[11];
    const float w203 = Small[12], w204 = Small[13], w205 = Small[14];
    const float w210 = Small[15], w211 = Small[16], w212 = Small[17];
    const float w213 = Small[18], w214 = Small[19], w215 = Small[20];
    const float b2s0 = Small[21], b2s1 = Small[22];

    // all table reads complete before any wave writes G (overlaid region)
    __syncthreads();

    #pragma unroll
    for (int p = 0; p <= 4; ++p) {
        // tail rows 64..66 staged after p=0's reads (slots 0..2; rows 0..2 dead)
        if (p == 1 && l < 3) stage_row(S, x, b, tb, 64 + l);

        // ===== MFMA1: conv for G-columns 16p..16p+15 (p=4: col 64 only) =====
        const int ra = 16 * p + n + (g >> 1);
        bf16x8 bk0 = *(const bf16x8*)(S + (ra & 63) * 32 + (((g & 1) ^ ((ra >> 2) & 1)) << 4));
        bf16x8 bk1 = {0, 0, 0, 0, 0, 0, 0, 0};
        if (g < 2) {
            const int rb = 16 * p + n + 2;
            bk1 = *(const bf16x8*)(S + (rb & 63) * 32 + ((g ^ ((rb >> 2) & 1)) << 4));
        }

        f32x4 ac0 = {cbs0, cbs0, cbs0, cbs0};
        f32x4 ac1 = {cbs1, cbs1, cbs1, cbs1};
        f32x4 ac2 = {cbs2, cbs2, cbs2, cbs2};
        ac0 = MFMA16(A1[0], bk0, ac0); ac0 = MFMA16(A1[1], bk1, ac0);
        ac1 = MFMA16(A1[2], bk0, ac1); ac1 = MFMA16(A1[3], bk1, ac1);
        ac2 = MFMA16(A1[4], bk0, ac2); ac2 = MFMA16(A1[5], bk1, ac2);

        if (p < 4 || n == 0) {
            char* gc = G + ((16 * p + n) & 31) * 16 + ((g & 1) << 3) + ((g >> 1) ? GPLANE : 0);
            {
                uint2 w;
                w.x = pk2t(fmaf(-2.f, rcore(ac0.x), 1.f), fmaf(-2.f, rcore(ac0.y), 1.f));
                w.y = pk2t(fmaf(-2.f, rcore(ac0.z), 1.f), fmaf(-2.f, rcore(ac0.w), 1.f));
                *(uint2*)(gc + 0 * GPLANE) = w;
            }
            {
                uint2 w;
                w.x = pk2t(fmaf(-2.f, rcore(ac1.x), 1.f), fmaf(-2.f, rcore(ac1.y), 1.f));
                w.y = pk2t(fmaf(-2.f, rcore(ac1.z), 1.f), fmaf(-2.f, rcore(ac1.w), 1.f));
                *(uint2*)(gc + 2 * GPLANE) = w;
            }
            {
                uint2 w;
                w.x = pk2t(fmaf(-2.f, rcore(ac2.x), 1.f), fmaf(-2.f, rcore(ac2.y), 1.f));
                w.y = pk2t(fmaf(-2.f, rcore(ac2.z), 1.f), fmaf(-2.f, rcore(ac2.w), 1.f));
                *(uint2*)(gc + 4 * GPLANE) = w;
            }
        }

        // ===== MFMA2: FC1+FC2 for position tile p2=p-1 =====
        if (p >= 1) {
            const int p2 = p - 1;
            const int c0 = 16 * p2 + n;
            bf16x8 B0 = *(const bf16x8*)(G + g * GPLANE + (c0 & 31) * 16);
            bf16x8 B1 = (g < 2)
                ? *(const bf16x8*)(G + (4 + g) * GPLANE + (c0 & 31) * 16)
                : *(const bf16x8*)(G + (g - 2) * GPLANE + ((c0 + 1) & 31) * 16);
            bf16x8 B2 = *(const bf16x8*)(G + (2 + g) * GPLANE + ((c0 + 1) & 31) * 16);
            f32x4 h = {b1i0, b1i1, b1i2, b1i3};
            h = MFMA16(A2[0], B0, h);
            h = MFMA16(A2[1], B1, h);
            h = MFMA16(A2[2], B2, h);
            float t20 = fmaf(-2.f, rcore(h.x), 1.f);
            float t21 = fmaf(-2.f, rcore(h.y), 1.f);
            float t22 = fmaf(-2.f, rcore(h.z), 1.f);
            float t23 = fmaf(-2.f, rcore(h.w), 1.f);
            float u0 = __shfl(t20, n + 16, 64);
            float u1 = __shfl(t21, n + 16, 64);
            float y0 = b2s0 + w200 * t20 + w201 * t21 + w202 * t22 + w203 * t23
                            + w204 * u0 + w205 * u1;
            float y1 = b2s1 + w210 * t20 + w211 * t21 + w212 * t22 + w213 * t23
                            + w214 * u0 + w215 * u1;
            if (l < 16)
                reinterpret_cast<float2*>(out)[(size_t)b * TT + tb + 16 * p2 + n] =
                    make_float2(y0, y1);
        }
    }
}

extern "C" void kernel_launch(void* const* d_in, const int* in_sizes, int n_in,
                              void* d_out, int out_size, void* d_ws, size_t ws_size,
                              hipStream_t stream) {
    const float* x        = (const float*)d_in[0];
    const float* conv_w   = (const float*)d_in[1];
    const float* conv_b   = (const float*)d_in[2];
    const float* fc_hid_w = (const float*)d_in[3];
    const float* fc_hid_b = (const float*)d_in[4];
    const float* fc_out_w = (const float*)d_in[5];
    const float* fc_out_b = (const float*)d_in[6];
    float* out = (float*)d_out;

    const int grid = (BB * TT) / 256;   // 2048 blocks; LDS ~20KB -> up to 7 blocks/CU
    rvt_one<<<grid, 256, 0, stream>>>(x, conv_w, conv_b, fc_hid_w, fc_hid_b,
                                      fc_out_w, fc_out_b, out);
}

// Round 21
// 23.299 us; speedup vs baseline: 1.0825x; 1.0825x over previous
//
#include <hip/hip_runtime.h>

#define TT 16384
#define BB 32

typedef __attribute__((ext_vector_type(8))) short bf16x8;
typedef __attribute__((ext_vector_type(4))) float f32x4;

#define S1 2.8853900817779268f   // 2*log2(e)

// HOT pack: truncating, 1 VALU (v_perm_b32). Used everywhere now (<=1 ulp).
__device__ __forceinline__ unsigned int pk2t(float lo, float hi) {
#if __has_builtin(__builtin_amdgcn_perm)
    return __builtin_amdgcn_perm(__float_as_uint(hi), __float_as_uint(lo), 0x07060302u);
#else
    return (__float_as_uint(hi) & 0xFFFF0000u) | (__float_as_uint(lo) >> 16);
#endif
}
__device__ __forceinline__ float rcore(float v) {   // r = 1/(exp2(v)+1)
    return __builtin_amdgcn_rcpf(__builtin_amdgcn_exp2f(v) + 1.0f);
}

// ---------------- single fused kernel, 128 pos/wave, grid 1024 (round-19 base) ----------------
// Folded math (round-8-verified): G stores r = 1/(exp2(z)+1); FhwPad = -2*S1*w1,
// B1' = S1*b1 - 0.5*Sum(FhwPad_row) (in-block parallel reduction);
// W2' = -2*w2, B2' = b2 - 0.5*Sum(W2') — drops the fmaf(-2,r,1) per value.
__device__ __forceinline__ void stage_row(char* S, const float* __restrict__ x,
                                          int b, int tb, int i) {
    const int trow = tb - 3 + i;
    uint4 h0 = {0u, 0u, 0u, 0u}, h1 = {0u, 0u, 0u, 0u};
    if (trow >= 0 && trow < TT) {
        const float4* p = (const float4*)x + (size_t)(b * TT + trow) * 4;
        float4 f0 = p[0], f1 = p[1], f2 = p[2], f3 = p[3];
        h0.x = pk2t(f0.x, f0.y); h0.y = pk2t(f0.z, f0.w);
        h0.z = pk2t(f1.x, f1.y); h0.w = pk2t(f1.z, f1.w);
        h1.x = pk2t(f2.x, f2.y); h1.y = pk2t(f2.z, f2.w);
        h1.z = pk2t(f3.x, f3.y); h1.w = pk2t(f3.z, f3.w);
    }
    const int s = (i >> 2) & 1;
    char* base = S + (i & 63) * 32;
    *(uint4*)(base + s * 16) = h0;
    *(uint4*)(base + (s ^ 1) * 16) = h1;
}

#define MFMA16(a, bb, cc) __builtin_amdgcn_mfma_f32_16x16x32_bf16((a), (bb), (cc), 0, 0, 0)
#define GPLANE 512   // 32 cols * 16B

__global__ __launch_bounds__(256, 2) void rvt_one(
    const float* __restrict__ x,
    const float* __restrict__ conv_w, const float* __restrict__ conv_b,
    const float* __restrict__ fc_hid_w, const float* __restrict__ fc_hid_b,
    const float* __restrict__ fc_out_w, const float* __restrict__ fc_out_b,
    float* __restrict__ out)
{
    __shared__ __align__(16) char Sbuf[4 * 2048];
    __shared__ __align__(16) char Gbuf[4 * 3072];
    __shared__ __align__(16) float CwPad[576];    // [mt*4+r][48], S1-scaled, zero-padded
    __shared__ __align__(16) float FhwPad[576];   // [m<6][96], -2*S1-scaled
    __shared__ float Small[23];

    const int tid = threadIdx.x, wv = tid >> 6, l = tid & 63;
    const int n = l & 15, g = l >> 4;
    const int m = n;
    const int P0 = blockIdx.x << 9;               // 512 positions per block
    const int b  = P0 >> 14;
    const int tb = (P0 & (TT - 1)) + (wv << 7);   // 128 positions per wave

    char* S = Sbuf + wv * 2048;
    char* G = Gbuf + wv * 3072;

    // ---- prologue: stage rows 0..63 (rows tb-3 .. tb+60) ----
    stage_row(S, x, b, tb, l);

    // ---- build pre-scaled weight tables ----
    for (int i = tid; i < 576; i += 256) FhwPad[i] = -2.0f * S1 * fc_hid_w[i];
    for (int s = tid; s < 576; s += 256) {
        const int r = (s / 48) & 3, kcp = s % 48;
        if (!(r < 3 && kcp >= 14 && kcp <= 16)) CwPad[s] = 0.f;
    }
    if (tid < 27) {
        const int mt = tid / 9, r = (tid % 9) / 3, kc = tid % 3;
        CwPad[(mt * 4 + r) * 48 + 14 + kc] = S1 * conv_w[tid];
    } else if (tid < 30) Small[tid - 27] = S1 * conv_b[tid - 27];
    else if (tid < 36) Small[3 + tid - 30] = S1 * fc_hid_b[tid - 30];
    else if (tid < 48) Small[9 + tid - 36] = -2.0f * fc_out_w[tid - 36];
    else if (tid < 50) Small[21 + tid - 48] = fc_out_b[tid - 48];
    __syncthreads();

    // ---- fold Sum(w1) into B1' and Sum(w2) into B2' (one-time, parallel) ----
    if (tid < 96) {
        const int j = tid >> 4, s = tid & 15;
        float prt = 0.f;
        #pragma unroll
        for (int k = 0; k < 6; ++k) prt += FhwPad[j * 96 + s * 6 + k];
        prt += __shfl_xor(prt, 1, 16);
        prt += __shfl_xor(prt, 2, 16);
        prt += __shfl_xor(prt, 4, 16);
        prt += __shfl_xor(prt, 8, 16);
        if (s == 0) Small[3 + j] = fmaf(-0.5f, prt, Small[3 + j]);   // S1*b1 + S1*Sum(w1)
    } else if (tid >= 254) {
        const int k = tid - 254;
        float s2 = 0.f;
        #pragma unroll
        for (int j = 0; j < 6; ++j) s2 += Small[9 + k * 6 + j];
        Small[21 + k] = fmaf(-0.5f, s2, Small[21 + k]);              // b2 + Sum(w2)
    }

    // ---- per-lane A-fragment gather from LDS (truncating pack) ----
    union { uint4 u; bf16x8 f; } cv;
    bf16x8 A1[6], A2[3];
    #pragma unroll
    for (int mt = 0; mt < 3; ++mt)
        #pragma unroll
        for (int kt = 0; kt < 2; ++kt) {
            const int rr = kt * 2 + (g >> 1);
            const float* p = &CwPad[(mt * 4 + rr) * 48 + ((g & 1) * 8 - m + 15)];
            cv.u.x = pk2t(p[0], p[1]);
            cv.u.y = pk2t(p[2], p[3]);
            cv.u.z = pk2t(p[4], p[5]);
            cv.u.w = pk2t(p[6], p[7]);
            A1[mt * 2 + kt] = cv.f;
        }
    {
        const unsigned umask = (m < 6) ? 0xFFFFFFFFu : 0u;
        const int mc = (m < 6) ? m : 5;
        #pragma unroll
        for (int kt2 = 0; kt2 < 3; ++kt2) {
            const int q0 = kt2 * 32 + g * 8;
            const int wr = (q0 >= 48) ? 1 : 0;
            const int col0 = q0 - 48 * wr;
            const int oc = col0 >> 4, c0 = col0 & 15;
            const float4* fp = (const float4*)&FhwPad[mc * 96 + (oc * 2 + wr) * 16 + c0];
            float4 a = fp[0], bq = fp[1];
            cv.u.x = pk2t(a.x, a.y) & umask;
            cv.u.y = pk2t(a.z, a.w) & umask;
            cv.u.z = pk2t(bq.x, bq.y) & umask;
            cv.u.w = pk2t(bq.z, bq.w) & umask;
            A2[kt2] = cv.f;
        }
    }

    // ensure reduction writes to Small are visible before register reads below
    __syncthreads();

    const float cbs0 = Small[0], cbs1 = Small[1], cbs2 = Small[2];
    const int r0 = g * 4;
    const float b1i0 = (r0 + 0 < 6) ? Small[3 + r0 + 0] : 0.f;
    const float b1i1 = (r0 + 1 < 6) ? Small[3 + r0 + 1] : 0.f;
    const float b1i2 = (r0 + 2 < 6) ? Small[3 + r0 + 2] : 0.f;
    const float b1i3 = (r0 + 3 < 6) ? Small[3 + r0 + 3] : 0.f;
    const float w200 = Small[9],  w201 = Small[10], w202 = Small[11];
    const float w203 = Small[12], w204 = Small[13], w205 = Small[14];
    const float w210 = Small[15], w211 = Small[16], w212 = Small[17];
    const float w213 = Small[18], w214 = Small[19], w215 = Small[20];
    const float b2s0 = Small[21], b2s1 = Small[22];

    #pragma unroll
    for (int p = 0; p <= 8; ++p) {
        // ---- incremental staging (slots freed by tile p-1) ----
        if (p >= 1 && p <= 4) {
            if (l < 16) stage_row(S, x, b, tb, 48 + 16 * p + l);   // rows 64..127
        } else if (p == 5) {
            if (l < 3) stage_row(S, x, b, tb, 128 + l);            // rows 128..130
        }

        // ===== MFMA1: conv for G-columns 16p..16p+15 (p=8: col 128 only) =====
        const int ra = 16 * p + n + (g >> 1);
        bf16x8 bk0 = *(const bf16x8*)(S + (ra & 63) * 32 + (((g & 1) ^ ((ra >> 2) & 1)) << 4));
        bf16x8 bk1 = {0, 0, 0, 0, 0, 0, 0, 0};
        if (g < 2) {
            const int rb = 16 * p + n + 2;
            bk1 = *(const bf16x8*)(S + (rb & 63) * 32 + ((g ^ ((rb >> 2) & 1)) << 4));
        }

        f32x4 ac0 = {cbs0, cbs0, cbs0, cbs0};
        f32x4 ac1 = {cbs1, cbs1, cbs1, cbs1};
        f32x4 ac2 = {cbs2, cbs2, cbs2, cbs2};
        ac0 = MFMA16(A1[0], bk0, ac0); ac0 = MFMA16(A1[1], bk1, ac0);
        ac1 = MFMA16(A1[2], bk0, ac1); ac1 = MFMA16(A1[3], bk1, ac1);
        ac2 = MFMA16(A1[4], bk0, ac2); ac2 = MFMA16(A1[5], bk1, ac2);

        if (p < 8 || n == 0) {
            // G stores r directly (tanh affine terms folded into weights/biases)
            char* gc = G + ((16 * p + n) & 31) * 16 + ((g & 1) << 3) + ((g >> 1) ? GPLANE : 0);
            {
                uint2 w;
                w.x = pk2t(rcore(ac0.x), rcore(ac0.y));
                w.y = pk2t(rcore(ac0.z), rcore(ac0.w));
                *(uint2*)(gc + 0 * GPLANE) = w;
            }
            {
                uint2 w;
                w.x = pk2t(rcore(ac1.x), rcore(ac1.y));
                w.y = pk2t(rcore(ac1.z), rcore(ac1.w));
                *(uint2*)(gc + 2 * GPLANE) = w;
            }
            {
                uint2 w;
                w.x = pk2t(rcore(ac2.x), rcore(ac2.y));
                w.y = pk2t(rcore(ac2.z), rcore(ac2.w));
                *(uint2*)(gc + 4 * GPLANE) = w;
            }
        }

        // ===== MFMA2: FC1+FC2 for position tile p2=p-1 =====
        if (p >= 1) {
            const int p2 = p - 1;
            const int c0 = 16 * p2 + n;
            bf16x8 B0 = *(const bf16x8*)(G + g * GPLANE + (c0 & 31) * 16);
            bf16x8 B1 = (g < 2)
                ? *(const bf16x8*)(G + (4 + g) * GPLANE + (c0 & 31) * 16)
                : *(const bf16x8*)(G + (g - 2) * GPLANE + ((c0 + 1) & 31) * 16);
            bf16x8 B2 = *(const bf16x8*)(G + (2 + g) * GPLANE + ((c0 + 1) & 31) * 16);
            f32x4 h = {b1i0, b1i1, b1i2, b1i3};
            h = MFMA16(A2[0], B0, h);
            h = MFMA16(A2[1], B1, h);
            h = MFMA16(A2[2], B2, h);
            float r20 = rcore(h.x), r21 = rcore(h.y), r22 = rcore(h.z), r23 = rcore(h.w);
            float u0 = __shfl(r20, n + 16, 64);
            float u1 = __shfl(r21, n + 16, 64);
            float y0 = b2s0 + w200 * r20 + w201 * r21 + w202 * r22 + w203 * r23
                            + w204 * u0 + w205 * u1;
            float y1 = b2s1 + w210 * r20 + w211 * r21 + w212 * r22 + w213 * r23
                            + w214 * u0 + w215 * u1;
            if (l < 16)
                reinterpret_cast<float2*>(out)[(size_t)b * TT + tb + 16 * p2 + n] =
                    make_float2(y0, y1);
        }
    }
}

extern "C" void kernel_launch(void* const* d_in, const int* in_sizes, int n_in,
                              void* d_out, int out_size, void* d_ws, size_t ws_size,
                              hipStream_t stream) {
    const float* x        = (const float*)d_in[0];
    const float* conv_w   = (const float*)d_in[1];
    const float* conv_b   = (const float*)d_in[2];
    const float* fc_hid_w = (const float*)d_in[3];
    const float* fc_hid_b = (const float*)d_in[4];
    const float* fc_out_w = (const float*)d_in[5];
    const float* fc_out_b = (const float*)d_in[6];
    float* out = (float*)d_out;

    const int grid = (BB * TT) / 512;   // 1024 blocks = 4 blocks/CU, ONE batch
    rvt_one<<<grid, 256, 0, stream>>>(x, conv_w, conv_b, fc_hid_w, fc_hid_b,
                                      fc_out_w, fc_out_b, out);
}

// Round 22
// 22.362 us; speedup vs baseline: 1.1278x; 1.0419x over previous
//
#include <hip/hip_runtime.h>

#define TT 16384
#define BB 32

typedef __attribute__((ext_vector_type(8))) short bf16x8;
typedef __attribute__((ext_vector_type(4))) float f32x4;

#define S1 2.8853900817779268f   // 2*log2(e)

// HOT pack: truncating, 1 VALU (v_perm_b32). <=1 ulp vs RNE.
__device__ __forceinline__ unsigned int pk2t(float lo, float hi) {
#if __has_builtin(__builtin_amdgcn_perm)
    return __builtin_amdgcn_perm(__float_as_uint(hi), __float_as_uint(lo), 0x07060302u);
#else
    return (__float_as_uint(hi) & 0xFFFF0000u) | (__float_as_uint(lo) >> 16);
#endif
}
__device__ __forceinline__ float rcore(float v) {   // r = 1/(exp2(v)+1)
    return __builtin_amdgcn_rcpf(__builtin_amdgcn_exp2f(v) + 1.0f);
}

// ---------------- single fused kernel, 128 pos/wave, ALL staging in prologue ----------------
// S: flat 160-row buffer (rows 0..130 staged up-front; no ring, no mid-loop loads).
// G: 32-col ring (unchanged). Folded math (round-21-verified): G stores r.
__device__ __forceinline__ void stage_row(char* S, const float* __restrict__ x,
                                          int b, int tb, int i) {
    const int trow = tb - 3 + i;
    uint4 h0 = {0u, 0u, 0u, 0u}, h1 = {0u, 0u, 0u, 0u};
    if (trow >= 0 && trow < TT) {
        const float4* p = (const float4*)x + (size_t)(b * TT + trow) * 4;
        float4 f0 = p[0], f1 = p[1], f2 = p[2], f3 = p[3];
        h0.x = pk2t(f0.x, f0.y); h0.y = pk2t(f0.z, f0.w);
        h0.z = pk2t(f1.x, f1.y); h0.w = pk2t(f1.z, f1.w);
        h1.x = pk2t(f2.x, f2.y); h1.y = pk2t(f2.z, f2.w);
        h1.z = pk2t(f3.x, f3.y); h1.w = pk2t(f3.z, f3.w);
    }
    const int s = (i >> 2) & 1;
    char* base = S + i * 32;                 // flat: slot = row
    *(uint4*)(base + s * 16) = h0;
    *(uint4*)(base + (s ^ 1) * 16) = h1;
}

#define MFMA16(a, bb, cc) __builtin_amdgcn_mfma_f32_16x16x32_bf16((a), (bb), (cc), 0, 0, 0)
#define GPLANE 512    // 32 cols * 16B
#define SSTRIDE 5120  // 160 rows * 32B (reads up to row 145 at p=8 stay in-bounds)

__global__ __launch_bounds__(256, 2) void rvt_one(
    const float* __restrict__ x,
    const float* __restrict__ conv_w, const float* __restrict__ conv_b,
    const float* __restrict__ fc_hid_w, const float* __restrict__ fc_hid_b,
    const float* __restrict__ fc_out_w, const float* __restrict__ fc_out_b,
    float* __restrict__ out)
{
    __shared__ __align__(16) char Sbuf[4 * SSTRIDE];
    __shared__ __align__(16) char Gbuf[4 * 3072];
    __shared__ __align__(16) float CwPad[576];    // [mt*4+r][48], S1-scaled, zero-padded
    __shared__ __align__(16) float FhwPad[576];   // [m<6][96], -2*S1-scaled
    __shared__ float Small[23];

    const int tid = threadIdx.x, wv = tid >> 6, l = tid & 63;
    const int n = l & 15, g = l >> 4;
    const int m = n;
    const int P0 = blockIdx.x << 9;               // 512 positions per block
    const int b  = P0 >> 14;
    const int tb = (P0 & (TT - 1)) + (wv << 7);   // 128 positions per wave

    char* S = Sbuf + wv * SSTRIDE;
    char* G = Gbuf + wv * 3072;

    // ---- prologue: stage ALL rows 0..130 (rows tb-3 .. tb+127) up-front ----
    // Global loads issue back-to-back here; their latency hides under the
    // table build + reduction + A-gather below (~1500 cy of independent work).
    stage_row(S, x, b, tb, l);
    stage_row(S, x, b, tb, l + 64);
    if (l < 3) stage_row(S, x, b, tb, l + 128);

    // ---- build pre-scaled weight tables ----
    for (int i = tid; i < 576; i += 256) FhwPad[i] = -2.0f * S1 * fc_hid_w[i];
    for (int s = tid; s < 576; s += 256) {
        const int r = (s / 48) & 3, kcp = s % 48;
        if (!(r < 3 && kcp >= 14 && kcp <= 16)) CwPad[s] = 0.f;
    }
    if (tid < 27) {
        const int mt = tid / 9, r = (tid % 9) / 3, kc = tid % 3;
        CwPad[(mt * 4 + r) * 48 + 14 + kc] = S1 * conv_w[tid];
    } else if (tid < 30) Small[tid - 27] = S1 * conv_b[tid - 27];
    else if (tid < 36) Small[3 + tid - 30] = S1 * fc_hid_b[tid - 30];
    else if (tid < 48) Small[9 + tid - 36] = -2.0f * fc_out_w[tid - 36];
    else if (tid < 50) Small[21 + tid - 48] = fc_out_b[tid - 48];
    __syncthreads();

    // ---- fold Sum(w1) into B1' and Sum(w2) into B2' (one-time, parallel) ----
    if (tid < 96) {
        const int j = tid >> 4, s = tid & 15;
        float prt = 0.f;
        #pragma unroll
        for (int k = 0; k < 6; ++k) prt += FhwPad[j * 96 + s * 6 + k];
        prt += __shfl_xor(prt, 1, 16);
        prt += __shfl_xor(prt, 2, 16);
        prt += __shfl_xor(prt, 4, 16);
        prt += __shfl_xor(prt, 8, 16);
        if (s == 0) Small[3 + j] = fmaf(-0.5f, prt, Small[3 + j]);
    } else if (tid >= 254) {
        const int k = tid - 254;
        float s2 = 0.f;
        #pragma unroll
        for (int j = 0; j < 6; ++j) s2 += Small[9 + k * 6 + j];
        Small[21 + k] = fmaf(-0.5f, s2, Small[21 + k]);
    }

    // ---- per-lane A-fragment gather from LDS (truncating pack) ----
    union { uint4 u; bf16x8 f; } cv;
    bf16x8 A1[6], A2[3];
    #pragma unroll
    for (int mt = 0; mt < 3; ++mt)
        #pragma unroll
        for (int kt = 0; kt < 2; ++kt) {
            const int rr = kt * 2 + (g >> 1);
            const float* p = &CwPad[(mt * 4 + rr) * 48 + ((g & 1) * 8 - m + 15)];
            cv.u.x = pk2t(p[0], p[1]);
            cv.u.y = pk2t(p[2], p[3]);
            cv.u.z = pk2t(p[4], p[5]);
            cv.u.w = pk2t(p[6], p[7]);
            A1[mt * 2 + kt] = cv.f;
        }
    {
        const unsigned umask = (m < 6) ? 0xFFFFFFFFu : 0u;
        const int mc = (m < 6) ? m : 5;
        #pragma unroll
        for (int kt2 = 0; kt2 < 3; ++kt2) {
            const int q0 = kt2 * 32 + g * 8;
            const int wr = (q0 >= 48) ? 1 : 0;
            const int col0 = q0 - 48 * wr;
            const int oc = col0 >> 4, c0 = col0 & 15;
            const float4* fp = (const float4*)&FhwPad[mc * 96 + (oc * 2 + wr) * 16 + c0];
            float4 a = fp[0], bq = fp[1];
            cv.u.x = pk2t(a.x, a.y) & umask;
            cv.u.y = pk2t(a.z, a.w) & umask;
            cv.u.z = pk2t(bq.x, bq.y) & umask;
            cv.u.w = pk2t(bq.z, bq.w) & umask;
            A2[kt2] = cv.f;
        }
    }

    // reduction writes to Small visible before reads below
    __syncthreads();

    const float cbs0 = Small[0], cbs1 = Small[1], cbs2 = Small[2];
    const int r0 = g * 4;
    const float b1i0 = (r0 + 0 < 6) ? Small[3 + r0 + 0] : 0.f;
    const float b1i1 = (r0 + 1 < 6) ? Small[3 + r0 + 1] : 0.f;
    const float b1i2 = (r0 + 2 < 6) ? Small[3 + r0 + 2] : 0.f;
    const float b1i3 = (r0 + 3 < 6) ? Small[3 + r0 + 3] : 0.f;
    const float w200 = Small[9],  w201 = Small[10], w202 = Small[11];
    const float w203 = Small[12], w204 = Small[13], w205 = Small[14];
    const float w210 = Small[15], w211 = Small[16], w212 = Small[17];
    const float w213 = Small[18], w214 = Small[19], w215 = Small[20];
    const float b2s0 = Small[21], b2s1 = Small[22];

    #pragma unroll
    for (int p = 0; p <= 8; ++p) {
        // ===== MFMA1: conv for G-columns 16p..16p+15 (p=8: col 128 only) =====
        const int ra = 16 * p + n + (g >> 1);
        bf16x8 bk0 = *(const bf16x8*)(S + ra * 32 + (((g & 1) ^ ((ra >> 2) & 1)) << 4));
        bf16x8 bk1 = {0, 0, 0, 0, 0, 0, 0, 0};
        if (g < 2) {
            const int rb = 16 * p + n + 2;
            bk1 = *(const bf16x8*)(S + rb * 32 + ((g ^ ((rb >> 2) & 1)) << 4));
        }

        f32x4 ac0 = {cbs0, cbs0, cbs0, cbs0};
        f32x4 ac1 = {cbs1, cbs1, cbs1, cbs1};
        f32x4 ac2 = {cbs2, cbs2, cbs2, cbs2};
        ac0 = MFMA16(A1[0], bk0, ac0); ac0 = MFMA16(A1[1], bk1, ac0);
        ac1 = MFMA16(A1[2], bk0, ac1); ac1 = MFMA16(A1[3], bk1, ac1);
        ac2 = MFMA16(A1[4], bk0, ac2); ac2 = MFMA16(A1[5], bk1, ac2);

        if (p < 8 || n == 0) {
            // G stores r directly (tanh affine terms folded into weights/biases)
            char* gc = G + ((16 * p + n) & 31) * 16 + ((g & 1) << 3) + ((g >> 1) ? GPLANE : 0);
            {
                uint2 w;
                w.x = pk2t(rcore(ac0.x), rcore(ac0.y));
                w.y = pk2t(rcore(ac0.z), rcore(ac0.w));
                *(uint2*)(gc + 0 * GPLANE) = w;
            }
            {
                uint2 w;
                w.x = pk2t(rcore(ac1.x), rcore(ac1.y));
                w.y = pk2t(rcore(ac1.z), rcore(ac1.w));
                *(uint2*)(gc + 2 * GPLANE) = w;
            }
            {
                uint2 w;
                w.x = pk2t(rcore(ac2.x), rcore(ac2.y));
                w.y = pk2t(rcore(ac2.z), rcore(ac2.w));
                *(uint2*)(gc + 4 * GPLANE) = w;
            }
        }

        // ===== MFMA2: FC1+FC2 for position tile p2=p-1 =====
        if (p >= 1) {
            const int p2 = p - 1;
            const int c0 = 16 * p2 + n;
            bf16x8 B0 = *(const bf16x8*)(G + g * GPLANE + (c0 & 31) * 16);
            bf16x8 B1 = (g < 2)
                ? *(const bf16x8*)(G + (4 + g) * GPLANE + (c0 & 31) * 16)
                : *(const bf16x8*)(G + (g - 2) * GPLANE + ((c0 + 1) & 31) * 16);
            bf16x8 B2 = *(const bf16x8*)(G + (2 + g) * GPLANE + ((c0 + 1) & 31) * 16);
            f32x4 h = {b1i0, b1i1, b1i2, b1i3};
            h = MFMA16(A2[0], B0, h);
            h = MFMA16(A2[1], B1, h);
            h = MFMA16(A2[2], B2, h);
            float r20 = rcore(h.x), r21 = rcore(h.y), r22 = rcore(h.z), r23 = rcore(h.w);
            float u0 = __shfl(r20, n + 16, 64);
            float u1 = __shfl(r21, n + 16, 64);
            float y0 = b2s0 + w200 * r20 + w201 * r21 + w202 * r22 + w203 * r23
                            + w204 * u0 + w205 * u1;
            float y1 = b2s1 + w210 * r20 + w211 * r21 + w212 * r22 + w213 * r23
                            + w214 * u0 + w215 * u1;
            if (l < 16)
                reinterpret_cast<float2*>(out)[(size_t)b * TT + tb + 16 * p2 + n] =
                    make_float2(y0, y1);
        }
    }
}

extern "C" void kernel_launch(void* const* d_in, const int* in_sizes, int n_in,
                              void* d_out, int out_size, void* d_ws, size_t ws_size,
                              hipStream_t stream) {
    const float* x        = (const float*)d_in[0];
    const float* conv_w   = (const float*)d_in[1];
    const float* conv_b   = (const float*)d_in[2];
    const float* fc_hid_w = (const float*)d_in[3];
    const float* fc_hid_b = (const float*)d_in[4];
    const float* fc_out_w = (const float*)d_in[5];
    const float* fc_out_b = (const float*)d_in[6];
    float* out = (float*)d_out;

    const int grid = (BB * TT) / 512;   // 1024 blocks = 4 blocks/CU, ONE batch
    rvt_one<<<grid, 256, 0, stream>>>(x, conv_w, conv_b, fc_hid_w, fc_hid_b,
                                      fc_out_w, fc_out_b, out);
}